// Round 8
// baseline (493.231 us; speedup 1.0000x reference)
//
#include <hip/hip_runtime.h>
#include <math.h>

#define NSP 8
#define NSLOT 256          // scalar-accumulator slots, 128B apart (32 floats)

typedef float v4f __attribute__((ext_vector_type(4)));

// ---------------- node 1: build ps, zero out + slots + ticket ----------------
__global__ __launch_bounds__(256) void init_kernel(
    const float* __restrict__ pos, const int* __restrict__ spec,
    v4f* __restrict__ ps, float* __restrict__ slots /* NSLOT*32 floats + ticket */,
    float* __restrict__ out, int n_atoms, int out_sz)
{
    const int t  = blockIdx.x * 256 + threadIdx.x;
    const int gs = gridDim.x * 256;
    for (int a = t; a < n_atoms; a += gs) {
        v4f v;
        v.x = pos[3 * a];
        v.y = pos[3 * a + 1];
        v.z = pos[3 * a + 2];
        v.w = __int_as_float(spec[a]);
        ps[a] = v;
    }
    for (int k = t; k < out_sz; k += gs) out[k] = 0.f;
    for (int k = t; k < NSLOT * 32 + 32; k += gs) slots[k] = 0.f;  // +ticket line
}

// ---------------- node 2: pairs + direct f32 atomics + last-block finalize ----
// Hot loop identical to R5's validated 61us kernel. Scalars: shuffle tree ->
// 7 atomics into blockIdx&255 slot (cache-line-spread: R1-R4's 300us mystery
// was 87K same-LINE atomics serializing at ~3.5ns each on one TCC channel).
// Last block (ticket, no spinning) reduces slots -> energy + stress.
__global__ __launch_bounds__(256, 8) void pair_kernel(
    const v4f* __restrict__ ps,
    const float* __restrict__ cell,
    const float* __restrict__ sigma_m,
    const float* __restrict__ eps_m,
    const float* __restrict__ alpha_m,
    const float* __restrict__ shifts,
    const int* __restrict__ mapping,
    float* __restrict__ slots,               // NSLOT*32 floats, ticket at [NSLOT*32]
    float* __restrict__ out,
    int n_atoms, int n_pairs)
{
    __shared__ float s_sigma[64], s_invsig[64], s_alpha[64], s_eoa[64], s_eos[64];
    __shared__ float s_cell[9];
    const int t = threadIdx.x;
    if (t < 64) {
        float sg = sigma_m[t], ep = eps_m[t], al = alpha_m[t];
        s_sigma[t]  = sg;
        s_invsig[t] = 1.0f / sg;
        s_alpha[t]  = al;
        s_eoa[t]    = ep / al;
        s_eos[t]    = ep / sg;
    }
    if (t < 9) s_cell[t] = cell[t];
    __syncthreads();

    const int p = blockIdx.x * 256 + t;
    float le = 0.f, s00 = 0.f, s01 = 0.f, s02 = 0.f, s11 = 0.f, s12 = 0.f, s22 = 0.f;

    float* __restrict__ energies = out + 1;
    float* __restrict__ forces   = out + 1 + n_atoms;

    if (p < n_pairs) {
        const int i = mapping[p];
        const int j = mapping[p + n_pairs];
        const float shx = shifts[3 * p];
        const float shy = shifts[3 * p + 1];
        const float shz = shifts[3 * p + 2];

        const v4f pi = ps[i];
        const v4f pj = ps[j];

        const float drx = pj.x - pi.x + shx * s_cell[0] + shy * s_cell[3] + shz * s_cell[6];
        const float dry = pj.y - pi.y + shx * s_cell[1] + shy * s_cell[4] + shz * s_cell[7];
        const float drz = pj.z - pi.z + shx * s_cell[2] + shy * s_cell[5] + shz * s_cell[8];
        const float r = sqrtf(drx * drx + dry * dry + drz * drz);

        const int idx = __float_as_int(pi.w) * NSP + __float_as_int(pj.w);
        if (r < s_sigma[idx]) {
            const float base = 1.0f - r * s_invsig[idx];
            const float pb   = __powf(base, s_alpha[idx] - 1.0f);
            const float e    = s_eoa[idx] * pb * base;
            const float sc   = s_eos[idx] * pb / r;
            const float fx = sc * drx, fy = sc * dry, fz = sc * drz;

            le  = e;
            s00 = drx * fx; s01 = drx * fy; s02 = drx * fz;
            s11 = dry * fy; s12 = dry * fz; s22 = drz * fz;

            const float he = 0.5f * e;
            atomicAdd(&energies[i], he);
            atomicAdd(&energies[j], he);
            atomicAdd(&forces[3 * i],     fx);
            atomicAdd(&forces[3 * i + 1], fy);
            atomicAdd(&forces[3 * i + 2], fz);
            atomicAdd(&forces[3 * j],     -fx);
            atomicAdd(&forces[3 * j + 1], -fy);
            atomicAdd(&forces[3 * j + 2], -fz);
        }
    }

    // ---- block reduction: shuffle tree (R5-validated; beats LDS atomics R6) ----
    {
        float vals[7] = {le, s00, s01, s02, s11, s12, s22};
        #pragma unroll
        for (int k = 0; k < 7; ++k) {
            float v = vals[k];
            #pragma unroll
            for (int off = 32; off > 0; off >>= 1)
                v += __shfl_down(v, off, 64);
            vals[k] = v;
        }
        __shared__ float s_red[4][7];
        const int wave = t >> 6, lane = t & 63;
        if (lane == 0) {
            #pragma unroll
            for (int k = 0; k < 7; ++k) s_red[wave][k] = vals[k];
        }
        __syncthreads();
        if (t < 7) {
            const float v = s_red[0][t] + s_red[1][t] + s_red[2][t] + s_red[3][t];
            atomicAdd(&slots[(size_t)(blockIdx.x & (NSLOT - 1)) * 32 + t], v);
        }
    }

    // ---- ticket: last block to finish reduces the slots (no spinning) ----
    __shared__ unsigned s_last;
    __syncthreads();
    if (t == 0) {
        __threadfence();                      // release: slot/out atomics before ticket
        unsigned* ticket = (unsigned*)(slots + (size_t)NSLOT * 32);
        const unsigned old = atomicAdd(ticket, 1u);
        s_last = (old == gridDim.x - 1) ? 1u : 0u;
    }
    __syncthreads();

    if (s_last) {
        __threadfence();                      // acquire side
        // thread t owns slot t: device-coherent reads via atomic no-op add
        float vals[7];
        #pragma unroll
        for (int k = 0; k < 7; ++k)
            vals[k] = atomicAdd(&slots[(size_t)t * 32 + k], 0.0f);
        #pragma unroll
        for (int k = 0; k < 7; ++k) {
            float v = vals[k];
            #pragma unroll
            for (int off = 32; off > 0; off >>= 1)
                v += __shfl_down(v, off, 64);
            vals[k] = v;
        }
        __shared__ float s_red2[4][7];
        const int wave = t >> 6, lane = t & 63;
        if (lane == 0) {
            #pragma unroll
            for (int k = 0; k < 7; ++k) s_red2[wave][k] = vals[k];
        }
        __syncthreads();
        if (t == 0) {
            float tot[7];
            #pragma unroll
            for (int k = 0; k < 7; ++k)
                tot[k] = s_red2[0][k] + s_red2[1][k] + s_red2[2][k] + s_red2[3][k];
            out[0] = 0.5f * tot[0];
            const float c0 = s_cell[0], c1 = s_cell[1], c2 = s_cell[2];
            const float c3 = s_cell[3], c4 = s_cell[4], c5 = s_cell[5];
            const float c6 = s_cell[6], c7 = s_cell[7], c8 = s_cell[8];
            const float det = c0 * (c4 * c8 - c5 * c7)
                            - c1 * (c3 * c8 - c5 * c6)
                            + c2 * (c3 * c7 - c4 * c6);
            const float nv = -1.0f / fabsf(det);
            float* st = out + 1 + 4 * n_atoms;
            st[0] = tot[1] * nv;  st[1] = tot[2] * nv;  st[2] = tot[3] * nv;
            st[3] = tot[2] * nv;  st[4] = tot[4] * nv;  st[5] = tot[5] * nv;
            st[6] = tot[3] * nv;  st[7] = tot[5] * nv;  st[8] = tot[6] * nv;
        }
    }
}

// ---------------- last-resort fallback (ws too small) ----------------
__global__ __launch_bounds__(256) void soft_sphere_fallback(
    const float* __restrict__ positions, const float* __restrict__ cell,
    const float* __restrict__ sigma_m, const float* __restrict__ eps_m,
    const float* __restrict__ alpha_m, const float* __restrict__ shifts,
    const int* __restrict__ mapping, const int* __restrict__ species,
    float* __restrict__ out, int n_atoms, int n_pairs)
{
    __shared__ float s_sigma[64], s_invsig[64], s_alpha[64], s_eoa[64], s_eos[64];
    __shared__ float s_cell[9];
    const int t = threadIdx.x;
    if (t < 64) {
        float sg = sigma_m[t], ep = eps_m[t], al = alpha_m[t];
        s_sigma[t] = sg; s_invsig[t] = 1.0f / sg; s_alpha[t] = al;
        s_eoa[t] = ep / al; s_eos[t] = ep / sg;
    }
    if (t < 9) s_cell[t] = cell[t];
    __syncthreads();

    float* energies = out + 1;
    float* forces   = out + 1 + n_atoms;
    float* stress   = out + 1 + 4 * n_atoms;

    float le = 0.f, s00 = 0.f, s01 = 0.f, s02 = 0.f, s11 = 0.f, s12 = 0.f, s22 = 0.f;
    const int stride = blockDim.x * gridDim.x;
    for (int p = blockIdx.x * blockDim.x + t; p < n_pairs; p += stride) {
        const int i = mapping[p], j = mapping[p + n_pairs];
        const float drx = positions[3*j]   - positions[3*i]   + shifts[3*p]*s_cell[0] + shifts[3*p+1]*s_cell[3] + shifts[3*p+2]*s_cell[6];
        const float dry = positions[3*j+1] - positions[3*i+1] + shifts[3*p]*s_cell[1] + shifts[3*p+1]*s_cell[4] + shifts[3*p+2]*s_cell[7];
        const float drz = positions[3*j+2] - positions[3*i+2] + shifts[3*p]*s_cell[2] + shifts[3*p+1]*s_cell[5] + shifts[3*p+2]*s_cell[8];
        const float r = sqrtf(drx*drx + dry*dry + drz*drz);
        const int idx = species[i] * NSP + species[j];
        if (r < s_sigma[idx]) {
            const float base = 1.0f - r * s_invsig[idx];
            const float pb = __powf(base, s_alpha[idx] - 1.0f);
            const float e = s_eoa[idx] * pb * base;
            const float sc = s_eos[idx] * pb / r;
            const float fx = sc*drx, fy = sc*dry, fz = sc*drz;
            le += e;
            s00 += drx*fx; s01 += drx*fy; s02 += drx*fz;
            s11 += dry*fy; s12 += dry*fz; s22 += drz*fz;
            atomicAdd(&energies[i], 0.5f*e); atomicAdd(&energies[j], 0.5f*e);
            atomicAdd(&forces[3*i], fx); atomicAdd(&forces[3*i+1], fy); atomicAdd(&forces[3*i+2], fz);
            atomicAdd(&forces[3*j], -fx); atomicAdd(&forces[3*j+1], -fy); atomicAdd(&forces[3*j+2], -fz);
        }
    }
    float vals[7] = {le, s00, s01, s02, s11, s12, s22};
    #pragma unroll
    for (int k = 0; k < 7; ++k) {
        float v = vals[k];
        #pragma unroll
        for (int off = 32; off > 0; off >>= 1) v += __shfl_down(v, off, 64);
        vals[k] = v;
    }
    __shared__ float s_red[4][7];
    const int wave = t >> 6, lane = t & 63;
    if (lane == 0) for (int k = 0; k < 7; ++k) s_red[wave][k] = vals[k];
    __syncthreads();
    if (t == 0) {
        const int nwaves = blockDim.x >> 6;
        float tot[7];
        for (int k = 0; k < 7; ++k) {
            float v = s_red[0][k];
            for (int w = 1; w < nwaves; ++w) v += s_red[w][k];
            tot[k] = v;
        }
        atomicAdd(&out[0], 0.5f * tot[0]);
        const float det = s_cell[0]*(s_cell[4]*s_cell[8]-s_cell[5]*s_cell[7])
                        - s_cell[1]*(s_cell[3]*s_cell[8]-s_cell[5]*s_cell[6])
                        + s_cell[2]*(s_cell[3]*s_cell[7]-s_cell[4]*s_cell[6]);
        const float nv = -1.0f / fabsf(det);
        atomicAdd(&stress[0], tot[1]*nv); atomicAdd(&stress[1], tot[2]*nv); atomicAdd(&stress[2], tot[3]*nv);
        atomicAdd(&stress[3], tot[2]*nv); atomicAdd(&stress[4], tot[4]*nv); atomicAdd(&stress[5], tot[5]*nv);
        atomicAdd(&stress[6], tot[3]*nv); atomicAdd(&stress[7], tot[5]*nv); atomicAdd(&stress[8], tot[6]*nv);
    }
}

extern "C" void kernel_launch(void* const* d_in, const int* in_sizes, int n_in,
                              void* d_out, int out_size, void* d_ws, size_t ws_size,
                              hipStream_t stream) {
    const float* positions = (const float*)d_in[0];
    const float* cell      = (const float*)d_in[1];
    const float* sigma_m   = (const float*)d_in[2];
    const float* eps_m     = (const float*)d_in[3];
    const float* alpha_m   = (const float*)d_in[4];
    const float* shifts    = (const float*)d_in[5];
    const int*   mapping   = (const int*)d_in[6];
    const int*   species   = (const int*)d_in[7];
    float* out = (float*)d_out;

    const int n_atoms = in_sizes[0] / 3;
    const int n_pairs = in_sizes[6] / 2;

    // ws layout: ps [n*16] | slots [NSLOT*32 floats] | ticket line [128B]
    const size_t off_ps    = 0;
    const size_t off_slots = off_ps + (size_t)n_atoms * 16;
    const size_t need      = off_slots + (size_t)NSLOT * 32 * 4 + 128;

    if (ws_size < need) {
        hipMemsetAsync(d_out, 0, (size_t)out_size * sizeof(float), stream);
        int blocks = ((n_pairs + 3) / 4 + 255) / 256;
        soft_sphere_fallback<<<blocks, 256, 0, stream>>>(
            positions, cell, sigma_m, eps_m, alpha_m, shifts, mapping, species,
            out, n_atoms, n_pairs);
        return;
    }

    char* wsb = (char*)d_ws;
    v4f*   ps    = (v4f*)(wsb + off_ps);
    float* slots = (float*)(wsb + off_slots);

    const int init_blocks = (out_size + 255) / 256;   // covers out, atoms, slots
    init_kernel<<<init_blocks, 256, 0, stream>>>(
        positions, species, ps, slots, out, n_atoms, out_size);

    const int pk_blocks = (n_pairs + 255) / 256;      // one pair per thread
    pair_kernel<<<pk_blocks, 256, 0, stream>>>(
        ps, cell, sigma_m, eps_m, alpha_m, shifts, mapping,
        slots, out, n_atoms, n_pairs);
}

// Round 9
// 169.200 us; speedup vs baseline: 2.9151x; 2.9151x over previous
//
#include <hip/hip_runtime.h>
#include <math.h>

#define NSP 8

typedef float v4f __attribute__((ext_vector_type(4)));

// Fixed-point packing (validated rounds 3-6, absmax 0.0039):
//  accum is 2x u64 per atom (ONE 16B cache-line chunk -> 2 lines touched/pair):
//   A = sum of ( (fx+2)*2^20 )<<32 | ( (fy+2)*2^20 )
//   B = (count)<<56 | ( he*2^17 )<<32 (24-bit field) | ( (fz+2)*2^20 )
// Hard-won rules encoded in this structure:
//  - NO same-address global atomics from many blocks (~3.5 ns/op TCC serialization: R1-R4)
//  - NO __threadfence / ticket / cooperative launch (L2-coherence storms: R7, R8)
//  - u64-packed atomics into ws beat f32 atomics into out by ~2.8x (R3 vs R1, R8)
//  - shuffle-tree block reduction beats LDS same-address atomics (R6)
//  - 1 pair/thread (max waves) beats 4 pairs/thread (R5)
#define FSCALE 1048576.0f        /* 2^20 */
#define FINV   (1.0f/1048576.0f)
#define ESCALE 131072.0f         /* 2^17 */
#define EINV   (1.0f/131072.0f)
#define FBIAS  2.0f

// ---------------- node 1: repack positions+species -> ps; zero accum ----------
__global__ __launch_bounds__(256) void init_kernel(
    const float* __restrict__ pos, const int* __restrict__ spec,
    v4f* __restrict__ ps, unsigned long long* __restrict__ accum, int n)
{
    int t = blockIdx.x * blockDim.x + threadIdx.x;
    if (t < n) {
        v4f v;
        v.x = pos[3 * t];
        v.y = pos[3 * t + 1];
        v.z = pos[3 * t + 2];
        v.w = __int_as_float(spec[t]);
        ps[t] = v;
        accum[2 * t]     = 0ULL;
        accum[2 * t + 1] = 0ULL;
    }
}

// ---------------- node 2: R5's validated pair kernel (61 us) ----------------
__global__ __launch_bounds__(256, 8) void pair_kernel(
    const v4f* __restrict__ ps,
    const float* __restrict__ cell,
    const float* __restrict__ sigma_m,
    const float* __restrict__ eps_m,
    const float* __restrict__ alpha_m,
    const float* __restrict__ shifts,
    const int* __restrict__ mapping,
    unsigned long long* __restrict__ accum,  // n_atoms x 2 u64 (pre-zeroed)
    float* __restrict__ partials,            // [gridDim.x * 8]
    int n_atoms, int n_pairs)
{
    __shared__ float s_sigma[64], s_invsig[64], s_alpha[64], s_eoa[64], s_eos[64];
    __shared__ float s_cell[9];
    const int t = threadIdx.x;
    if (t < 64) {
        float sg = sigma_m[t], ep = eps_m[t], al = alpha_m[t];
        s_sigma[t]  = sg;
        s_invsig[t] = 1.0f / sg;
        s_alpha[t]  = al;
        s_eoa[t]    = ep / al;
        s_eos[t]    = ep / sg;
    }
    if (t < 9) s_cell[t] = cell[t];
    __syncthreads();

    const int p = blockIdx.x * 256 + t;
    float le = 0.f, s00 = 0.f, s01 = 0.f, s02 = 0.f, s11 = 0.f, s12 = 0.f, s22 = 0.f;

    if (p < n_pairs) {
        const int i = mapping[p];
        const int j = mapping[p + n_pairs];
        const float shx = shifts[3 * p];
        const float shy = shifts[3 * p + 1];
        const float shz = shifts[3 * p + 2];

        const v4f pi = ps[i];
        const v4f pj = ps[j];

        const float drx = pj.x - pi.x + shx * s_cell[0] + shy * s_cell[3] + shz * s_cell[6];
        const float dry = pj.y - pi.y + shx * s_cell[1] + shy * s_cell[4] + shz * s_cell[7];
        const float drz = pj.z - pi.z + shx * s_cell[2] + shy * s_cell[5] + shz * s_cell[8];
        const float r = sqrtf(drx * drx + dry * dry + drz * drz);

        const int idx = __float_as_int(pi.w) * NSP + __float_as_int(pj.w);
        if (r < s_sigma[idx]) {
            const float base = 1.0f - r * s_invsig[idx];
            const float pb   = __powf(base, s_alpha[idx] - 1.0f);
            const float e    = s_eoa[idx] * pb * base;
            const float sc   = s_eos[idx] * pb / r;
            const float fx = sc * drx, fy = sc * dry, fz = sc * drz;

            le  = e;
            s00 = drx * fx; s01 = drx * fy; s02 = drx * fz;
            s11 = dry * fy; s12 = dry * fz; s22 = drz * fz;

            const float he = 0.5f * e;
            const unsigned long long he_fix = (unsigned long long)__float2uint_rn(he * ESCALE);
            {   // i side: +f
                const unsigned long long fxq = (unsigned long long)__float2uint_rn((fx + FBIAS) * FSCALE);
                const unsigned long long fyq = (unsigned long long)__float2uint_rn((fy + FBIAS) * FSCALE);
                const unsigned long long fzq = (unsigned long long)__float2uint_rn((fz + FBIAS) * FSCALE);
                atomicAdd(&accum[2 * i],     (fxq << 32) | fyq);
                atomicAdd(&accum[2 * i + 1], (1ULL << 56) | (he_fix << 32) | fzq);
            }
            {   // j side: -f
                const unsigned long long fxq = (unsigned long long)__float2uint_rn((FBIAS - fx) * FSCALE);
                const unsigned long long fyq = (unsigned long long)__float2uint_rn((FBIAS - fy) * FSCALE);
                const unsigned long long fzq = (unsigned long long)__float2uint_rn((FBIAS - fz) * FSCALE);
                atomicAdd(&accum[2 * j],     (fxq << 32) | fyq);
                atomicAdd(&accum[2 * j + 1], (1ULL << 56) | (he_fix << 32) | fzq);
            }
        }
    }

    // ---- block reduction: shuffle tree -> plain per-block partial store ----
    float vals[7] = {le, s00, s01, s02, s11, s12, s22};
    #pragma unroll
    for (int k = 0; k < 7; ++k) {
        float v = vals[k];
        #pragma unroll
        for (int off = 32; off > 0; off >>= 1)
            v += __shfl_down(v, off, 64);
        vals[k] = v;
    }
    __shared__ float s_red[4][7];
    const int wave = t >> 6, lane = t & 63;
    if (lane == 0) {
        #pragma unroll
        for (int k = 0; k < 7; ++k) s_red[wave][k] = vals[k];
    }
    __syncthreads();
    if (t < 8) {
        float v = 0.f;
        if (t < 7) v = s_red[0][t] + s_red[1][t] + s_red[2][t] + s_red[3][t];
        partials[(size_t)blockIdx.x * 8 + t] = v;
    }
}

// ---------------- node 3 (fused, R6-validated): block 0 reduces partials;
// blocks 1..N decode per-atom fixed-point accum -> out ----------------
__global__ __launch_bounds__(256) void finalize_kernel(
    const unsigned long long* __restrict__ accum,
    const float* __restrict__ partials, int nblocks,
    const float* __restrict__ cell, float* __restrict__ out, int n_atoms)
{
    if (blockIdx.x == 0) {
        const int t = threadIdx.x;
        float a0 = 0.f, a1 = 0.f, a2 = 0.f, a3 = 0.f, a4 = 0.f, a5 = 0.f, a6 = 0.f;
        for (int b = t; b < nblocks; b += 256) {
            const v4f lo = *(const v4f*)(partials + (size_t)b * 8);
            const v4f hi = *(const v4f*)(partials + (size_t)b * 8 + 4);
            a0 += lo.x; a1 += lo.y; a2 += lo.z; a3 += lo.w;
            a4 += hi.x; a5 += hi.y; a6 += hi.z;
        }
        float vals[7] = {a0, a1, a2, a3, a4, a5, a6};
        #pragma unroll
        for (int k = 0; k < 7; ++k) {
            float v = vals[k];
            #pragma unroll
            for (int off = 32; off > 0; off >>= 1)
                v += __shfl_down(v, off, 64);
            vals[k] = v;
        }
        __shared__ float s_red[4][7];
        const int wave = t >> 6, lane = t & 63;
        if (lane == 0) {
            #pragma unroll
            for (int k = 0; k < 7; ++k) s_red[wave][k] = vals[k];
        }
        __syncthreads();
        if (t == 0) {
            float tot[7];
            #pragma unroll
            for (int k = 0; k < 7; ++k)
                tot[k] = s_red[0][k] + s_red[1][k] + s_red[2][k] + s_red[3][k];
            out[0] = 0.5f * tot[0];
            const float c0 = cell[0], c1 = cell[1], c2 = cell[2];
            const float c3 = cell[3], c4 = cell[4], c5 = cell[5];
            const float c6 = cell[6], c7 = cell[7], c8 = cell[8];
            const float det = c0 * (c4 * c8 - c5 * c7)
                            - c1 * (c3 * c8 - c5 * c6)
                            + c2 * (c3 * c7 - c4 * c6);
            const float nv = -1.0f / fabsf(det);
            float* st = out + 1 + 4 * n_atoms;
            st[0] = tot[1] * nv;  st[1] = tot[2] * nv;  st[2] = tot[3] * nv;
            st[3] = tot[2] * nv;  st[4] = tot[4] * nv;  st[5] = tot[5] * nv;
            st[6] = tot[3] * nv;  st[7] = tot[5] * nv;  st[8] = tot[6] * nv;
        }
    } else {
        const int t = (blockIdx.x - 1) * 256 + threadIdx.x;
        if (t < n_atoms) {
            const unsigned long long A = accum[2 * t];
            const unsigned long long B = accum[2 * t + 1];
            const float cntb = (float)(unsigned)(B >> 56) * FBIAS;
            const float fx = (float)(unsigned)(A >> 32)          * FINV - cntb;
            const float fy = (float)(unsigned)(A & 0xFFFFFFFFu)  * FINV - cntb;
            const float fz = (float)(unsigned)(B & 0xFFFFFFFFu)  * FINV - cntb;
            const float he = (float)(unsigned)((B >> 32) & 0xFFFFFFu) * EINV;
            out[1 + t] = he;
            float* forces = out + 1 + n_atoms;
            forces[3 * t]     = fx;
            forces[3 * t + 1] = fy;
            forces[3 * t + 2] = fz;
        }
    }
}

// ---------------- last-resort fallback (ws too small) ----------------
__global__ __launch_bounds__(256) void soft_sphere_fallback(
    const float* __restrict__ positions, const float* __restrict__ cell,
    const float* __restrict__ sigma_m, const float* __restrict__ eps_m,
    const float* __restrict__ alpha_m, const float* __restrict__ shifts,
    const int* __restrict__ mapping, const int* __restrict__ species,
    float* __restrict__ out, int n_atoms, int n_pairs)
{
    __shared__ float s_sigma[64], s_invsig[64], s_alpha[64], s_eoa[64], s_eos[64];
    __shared__ float s_cell[9];
    const int t = threadIdx.x;
    if (t < 64) {
        float sg = sigma_m[t], ep = eps_m[t], al = alpha_m[t];
        s_sigma[t] = sg; s_invsig[t] = 1.0f / sg; s_alpha[t] = al;
        s_eoa[t] = ep / al; s_eos[t] = ep / sg;
    }
    if (t < 9) s_cell[t] = cell[t];
    __syncthreads();

    float* energies = out + 1;
    float* forces   = out + 1 + n_atoms;
    float* stress   = out + 1 + 4 * n_atoms;

    float le = 0.f, s00 = 0.f, s01 = 0.f, s02 = 0.f, s11 = 0.f, s12 = 0.f, s22 = 0.f;
    const int stride = blockDim.x * gridDim.x;
    for (int p = blockIdx.x * blockDim.x + t; p < n_pairs; p += stride) {
        const int i = mapping[p], j = mapping[p + n_pairs];
        const float drx = positions[3*j]   - positions[3*i]   + shifts[3*p]*s_cell[0] + shifts[3*p+1]*s_cell[3] + shifts[3*p+2]*s_cell[6];
        const float dry = positions[3*j+1] - positions[3*i+1] + shifts[3*p]*s_cell[1] + shifts[3*p+1]*s_cell[4] + shifts[3*p+2]*s_cell[7];
        const float drz = positions[3*j+2] - positions[3*i+2] + shifts[3*p]*s_cell[2] + shifts[3*p+1]*s_cell[5] + shifts[3*p+2]*s_cell[8];
        const float r = sqrtf(drx*drx + dry*dry + drz*drz);
        const int idx = species[i] * NSP + species[j];
        if (r < s_sigma[idx]) {
            const float base = 1.0f - r * s_invsig[idx];
            const float pb = __powf(base, s_alpha[idx] - 1.0f);
            const float e = s_eoa[idx] * pb * base;
            const float sc = s_eos[idx] * pb / r;
            const float fx = sc*drx, fy = sc*dry, fz = sc*drz;
            le += e;
            s00 += drx*fx; s01 += drx*fy; s02 += drx*fz;
            s11 += dry*fy; s12 += dry*fz; s22 += drz*fz;
            atomicAdd(&energies[i], 0.5f*e); atomicAdd(&energies[j], 0.5f*e);
            atomicAdd(&forces[3*i], fx); atomicAdd(&forces[3*i+1], fy); atomicAdd(&forces[3*i+2], fz);
            atomicAdd(&forces[3*j], -fx); atomicAdd(&forces[3*j+1], -fy); atomicAdd(&forces[3*j+2], -fz);
        }
    }
    float vals[7] = {le, s00, s01, s02, s11, s12, s22};
    #pragma unroll
    for (int k = 0; k < 7; ++k) {
        float v = vals[k];
        #pragma unroll
        for (int off = 32; off > 0; off >>= 1) v += __shfl_down(v, off, 64);
        vals[k] = v;
    }
    __shared__ float s_red[4][7];
    const int wave = t >> 6, lane = t & 63;
    if (lane == 0) for (int k = 0; k < 7; ++k) s_red[wave][k] = vals[k];
    __syncthreads();
    if (t == 0) {
        const int nwaves = blockDim.x >> 6;
        float tot[7];
        for (int k = 0; k < 7; ++k) {
            float v = s_red[0][k];
            for (int w = 1; w < nwaves; ++w) v += s_red[w][k];
            tot[k] = v;
        }
        atomicAdd(&out[0], 0.5f * tot[0]);
        const float det = s_cell[0]*(s_cell[4]*s_cell[8]-s_cell[5]*s_cell[7])
                        - s_cell[1]*(s_cell[3]*s_cell[8]-s_cell[5]*s_cell[6])
                        + s_cell[2]*(s_cell[3]*s_cell[7]-s_cell[4]*s_cell[6]);
        const float nv = -1.0f / fabsf(det);
        atomicAdd(&stress[0], tot[1]*nv); atomicAdd(&stress[1], tot[2]*nv); atomicAdd(&stress[2], tot[3]*nv);
        atomicAdd(&stress[3], tot[2]*nv); atomicAdd(&stress[4], tot[4]*nv); atomicAdd(&stress[5], tot[5]*nv);
        atomicAdd(&stress[6], tot[3]*nv); atomicAdd(&stress[7], tot[5]*nv); atomicAdd(&stress[8], tot[6]*nv);
    }
}

extern "C" void kernel_launch(void* const* d_in, const int* in_sizes, int n_in,
                              void* d_out, int out_size, void* d_ws, size_t ws_size,
                              hipStream_t stream) {
    const float* positions = (const float*)d_in[0];
    const float* cell      = (const float*)d_in[1];
    const float* sigma_m   = (const float*)d_in[2];
    const float* eps_m     = (const float*)d_in[3];
    const float* alpha_m   = (const float*)d_in[4];
    const float* shifts    = (const float*)d_in[5];
    const int*   mapping   = (const int*)d_in[6];
    const int*   species   = (const int*)d_in[7];
    float* out = (float*)d_out;

    const int n_atoms = in_sizes[0] / 3;
    const int n_pairs = in_sizes[6] / 2;

    const int pk_blocks = (n_pairs + 255) / 256;   // one pair per thread
    const int rp_blocks = (n_atoms + 255) / 256;

    // ws layout (16B-aligned): accum n*16 | ps n*16 | partials pk_blocks*32
    const size_t off_accum = 0;
    const size_t off_ps    = off_accum + (size_t)n_atoms * 16;
    const size_t off_part  = off_ps    + (size_t)n_atoms * 16;
    const size_t need      = off_part + (size_t)pk_blocks * 32;

    if (ws_size < need) {
        hipMemsetAsync(d_out, 0, (size_t)out_size * sizeof(float), stream);
        int blocks = ((n_pairs + 3) / 4 + 255) / 256;
        soft_sphere_fallback<<<blocks, 256, 0, stream>>>(
            positions, cell, sigma_m, eps_m, alpha_m, shifts, mapping, species,
            out, n_atoms, n_pairs);
        return;
    }

    char* wsb = (char*)d_ws;
    unsigned long long* accum    = (unsigned long long*)(wsb + off_accum);
    v4f*                ps       = (v4f*)(wsb + off_ps);
    float*              partials = (float*)(wsb + off_part);

    init_kernel<<<rp_blocks, 256, 0, stream>>>(positions, species, ps, accum, n_atoms);

    pair_kernel<<<pk_blocks, 256, 0, stream>>>(
        ps, cell, sigma_m, eps_m, alpha_m, shifts, mapping,
        accum, partials, n_atoms, n_pairs);

    finalize_kernel<<<1 + rp_blocks, 256, 0, stream>>>(
        accum, partials, pk_blocks, cell, out, n_atoms);
}

// Round 10
// 163.208 us; speedup vs baseline: 3.0221x; 1.0367x over previous
//
#include <hip/hip_runtime.h>
#include <math.h>

#define NSP 8
#define FBLOCKS 64   // finalize blocks; keeps same-line final atomics to ~640 ops (~5us)

typedef float v4f __attribute__((ext_vector_type(4)));

// Fixed-point packing (validated rounds 3-9, absmax 0.0039):
//  accum is 2x u64 per atom (one 16B chunk -> 2 lines touched per pair side):
//   A = sum of ( (fx+2)*2^20 )<<32 | ( (fy+2)*2^20 )
//   B = (count)<<56 | ( he*2^17 )<<32 (24-bit field) | ( (fz+2)*2^20 )
// Hard-won rules encoded in this structure:
//  - NO same-address global atomics from >~100 blocks (~12 ns/op TCC serialization: R1-R4)
//  - NO __threadfence / ticket / cooperative launch (L2-coherence storms: R7, R8)
//  - u64-packed atomics into ws beat f32 atomics into out (R3 vs R1/R8)
//  - shuffle-tree beats LDS same-address atomics (R6) — but this round the tree
//    is removed entirely: energy = sum_a he_a, stress = (sum_a r_a x F_a - K)/V
//    where K = sum_p (S.C) x f is nonzero only for pairs with nonzero shifts.
#define FSCALE 1048576.0f        /* 2^20 */
#define FINV   (1.0f/1048576.0f)
#define ESCALE 131072.0f         /* 2^17 */
#define EINV   (1.0f/131072.0f)
#define FBIAS  2.0f

// ---------------- node 1: repack pos+species -> ps; zero accum + scalar slots ----
__global__ __launch_bounds__(256) void init_kernel(
    const float* __restrict__ pos, const int* __restrict__ spec,
    v4f* __restrict__ ps, unsigned long long* __restrict__ accum,
    float* __restrict__ corr, float* __restrict__ out, int n_atoms)
{
    int t = blockIdx.x * blockDim.x + threadIdx.x;
    if (t < n_atoms) {
        v4f v;
        v.x = pos[3 * t];
        v.y = pos[3 * t + 1];
        v.z = pos[3 * t + 2];
        v.w = __int_as_float(spec[t]);
        ps[t] = v;
        accum[2 * t]     = 0ULL;
        accum[2 * t + 1] = 0ULL;
    }
    if (t == 0) out[0] = 0.f;
    if (t < 9) {
        out[1 + 4 * n_atoms + t] = 0.f;   // stress slots (finalize atomically adds)
        corr[t] = 0.f;                    // shift-correction accumulator
    }
}

// ---------------- node 2: pair kernel, NO block reduction ----------------
// Per-thread: 5 coalesced stream loads + 2 ps gathers + ~40 VALU; active lanes
// (~10.6%) add 4 u64 atomics. The 84-op shuffle tree of R5/R9 is gone —
// energy/stress are recovered per-atom in finalize (see header identity).
__global__ __launch_bounds__(256, 8) void pair_kernel(
    const v4f* __restrict__ ps,
    const float* __restrict__ cell,
    const float* __restrict__ sigma_m,
    const float* __restrict__ eps_m,
    const float* __restrict__ alpha_m,
    const float* __restrict__ shifts,
    const int* __restrict__ mapping,
    unsigned long long* __restrict__ accum,  // n_atoms x 2 u64 (pre-zeroed)
    float* __restrict__ corr,                // 9 floats (pre-zeroed)
    int n_atoms, int n_pairs)
{
    __shared__ float s_sigma[64], s_invsig[64], s_alpha[64], s_eoa[64], s_eos[64];
    __shared__ float s_cell[9];
    const int t = threadIdx.x;
    if (t < 64) {
        float sg = sigma_m[t], ep = eps_m[t], al = alpha_m[t];
        s_sigma[t]  = sg;
        s_invsig[t] = 1.0f / sg;
        s_alpha[t]  = al;
        s_eoa[t]    = ep / al;
        s_eos[t]    = ep / sg;
    }
    if (t < 9) s_cell[t] = cell[t];
    __syncthreads();

    const int p = blockIdx.x * 256 + t;
    if (p >= n_pairs) return;

    const int i = mapping[p];
    const int j = mapping[p + n_pairs];
    const float shx = shifts[3 * p];
    const float shy = shifts[3 * p + 1];
    const float shz = shifts[3 * p + 2];

    const v4f pi = ps[i];
    const v4f pj = ps[j];

    const float drx = pj.x - pi.x + shx * s_cell[0] + shy * s_cell[3] + shz * s_cell[6];
    const float dry = pj.y - pi.y + shx * s_cell[1] + shy * s_cell[4] + shz * s_cell[7];
    const float drz = pj.z - pi.z + shx * s_cell[2] + shy * s_cell[5] + shz * s_cell[8];
    const float r = sqrtf(drx * drx + dry * dry + drz * drz);

    const int idx = __float_as_int(pi.w) * NSP + __float_as_int(pj.w);
    if (r < s_sigma[idx]) {
        const float base = 1.0f - r * s_invsig[idx];
        const float pb   = __powf(base, s_alpha[idx] - 1.0f);
        const float e    = s_eoa[idx] * pb * base;
        const float sc   = s_eos[idx] * pb / r;
        const float fx = sc * drx, fy = sc * dry, fz = sc * drz;

        const float he = 0.5f * e;
        const unsigned long long he_fix = (unsigned long long)__float2uint_rn(he * ESCALE);
        {   // i side: +f
            const unsigned long long fxq = (unsigned long long)__float2uint_rn((fx + FBIAS) * FSCALE);
            const unsigned long long fyq = (unsigned long long)__float2uint_rn((fy + FBIAS) * FSCALE);
            const unsigned long long fzq = (unsigned long long)__float2uint_rn((fz + FBIAS) * FSCALE);
            atomicAdd(&accum[2 * i],     (fxq << 32) | fyq);
            atomicAdd(&accum[2 * i + 1], (1ULL << 56) | (he_fix << 32) | fzq);
        }
        {   // j side: -f
            const unsigned long long fxq = (unsigned long long)__float2uint_rn((FBIAS - fx) * FSCALE);
            const unsigned long long fyq = (unsigned long long)__float2uint_rn((FBIAS - fy) * FSCALE);
            const unsigned long long fzq = (unsigned long long)__float2uint_rn((FBIAS - fz) * FSCALE);
            atomicAdd(&accum[2 * j],     (fxq << 32) | fyq);
            atomicAdd(&accum[2 * j + 1], (1ULL << 56) | (he_fix << 32) | fzq);
        }

        // shift-correction K = sum (S.C) x f — only for nonzero shifts
        // (never taken in this workload; keeps the kernel fully general)
        if (shx != 0.f || shy != 0.f || shz != 0.f) {
            const float scx = shx * s_cell[0] + shy * s_cell[3] + shz * s_cell[6];
            const float scy = shx * s_cell[1] + shy * s_cell[4] + shz * s_cell[7];
            const float scz = shx * s_cell[2] + shy * s_cell[5] + shz * s_cell[8];
            atomicAdd(&corr[0], scx * fx); atomicAdd(&corr[1], scx * fy); atomicAdd(&corr[2], scx * fz);
            atomicAdd(&corr[3], scy * fx); atomicAdd(&corr[4], scy * fy); atomicAdd(&corr[5], scy * fz);
            atomicAdd(&corr[6], scz * fx); atomicAdd(&corr[7], scz * fy); atomicAdd(&corr[8], scz * fz);
        }
    }
}

// ---------------- node 3: decode accum -> out, and recover energy+stress ----
// energy = 0.5 * sum_a he_a;  stress = (sum_a r_a x F_a - K)/|det(cell)|
__global__ __launch_bounds__(256) void finalize_kernel(
    const unsigned long long* __restrict__ accum,
    const v4f* __restrict__ ps,
    const float* __restrict__ corr,
    const float* __restrict__ cell,
    float* __restrict__ out, int n_atoms)
{
    const int t  = threadIdx.x;
    const int gs = gridDim.x * 256;
    float se = 0.f, s00 = 0.f, s01 = 0.f, s02 = 0.f, s11 = 0.f, s12 = 0.f, s22 = 0.f;
    float* __restrict__ forces = out + 1 + n_atoms;

    for (int a = blockIdx.x * 256 + t; a < n_atoms; a += gs) {
        const unsigned long long A = accum[2 * a];
        const unsigned long long B = accum[2 * a + 1];
        const float cntb = (float)(unsigned)(B >> 56) * FBIAS;
        const float fx = (float)(unsigned)(A >> 32)          * FINV - cntb;
        const float fy = (float)(unsigned)(A & 0xFFFFFFFFu)  * FINV - cntb;
        const float fz = (float)(unsigned)(B & 0xFFFFFFFFu)  * FINV - cntb;
        const float he = (float)(unsigned)((B >> 32) & 0xFFFFFFu) * EINV;
        out[1 + a] = he;
        forces[3 * a]     = fx;
        forces[3 * a + 1] = fy;
        forces[3 * a + 2] = fz;

        const v4f pa = ps[a];
        se  += he;
        s00 += pa.x * fx; s01 += pa.x * fy; s02 += pa.x * fz;
        s11 += pa.y * fy; s12 += pa.y * fz; s22 += pa.z * fz;
    }

    // block shuffle-tree (7 values, 64 blocks only — cheap here)
    float vals[7] = {se, s00, s01, s02, s11, s12, s22};
    #pragma unroll
    for (int k = 0; k < 7; ++k) {
        float v = vals[k];
        #pragma unroll
        for (int off = 32; off > 0; off >>= 1)
            v += __shfl_down(v, off, 64);
        vals[k] = v;
    }
    __shared__ float s_red[4][7];
    const int wave = t >> 6, lane = t & 63;
    if (lane == 0) {
        #pragma unroll
        for (int k = 0; k < 7; ++k) s_red[wave][k] = vals[k];
    }
    __syncthreads();
    if (t == 0) {
        float tot[7];
        #pragma unroll
        for (int k = 0; k < 7; ++k)
            tot[k] = s_red[0][k] + s_red[1][k] + s_red[2][k] + s_red[3][k];

        const float c0 = cell[0], c1 = cell[1], c2 = cell[2];
        const float c3 = cell[3], c4 = cell[4], c5 = cell[5];
        const float c6 = cell[6], c7 = cell[7], c8 = cell[8];
        const float det = c0 * (c4 * c8 - c5 * c7)
                        - c1 * (c3 * c8 - c5 * c6)
                        + c2 * (c3 * c7 - c4 * c6);
        const float inv = 1.0f / fabsf(det);

        atomicAdd(&out[0], 0.5f * tot[0]);
        float* st = out + 1 + 4 * n_atoms;
        atomicAdd(&st[0], tot[1] * inv);  atomicAdd(&st[1], tot[2] * inv);  atomicAdd(&st[2], tot[3] * inv);
        atomicAdd(&st[3], tot[2] * inv);  atomicAdd(&st[4], tot[4] * inv);  atomicAdd(&st[5], tot[5] * inv);
        atomicAdd(&st[6], tot[3] * inv);  atomicAdd(&st[7], tot[5] * inv);  atomicAdd(&st[8], tot[6] * inv);

        if (blockIdx.x == 0) {
            #pragma unroll
            for (int k = 0; k < 9; ++k) atomicAdd(&st[k], -corr[k] * inv);
        }
    }
}

// ---------------- last-resort fallback (ws too small) ----------------
__global__ __launch_bounds__(256) void soft_sphere_fallback(
    const float* __restrict__ positions, const float* __restrict__ cell,
    const float* __restrict__ sigma_m, const float* __restrict__ eps_m,
    const float* __restrict__ alpha_m, const float* __restrict__ shifts,
    const int* __restrict__ mapping, const int* __restrict__ species,
    float* __restrict__ out, int n_atoms, int n_pairs)
{
    __shared__ float s_sigma[64], s_invsig[64], s_alpha[64], s_eoa[64], s_eos[64];
    __shared__ float s_cell[9];
    const int t = threadIdx.x;
    if (t < 64) {
        float sg = sigma_m[t], ep = eps_m[t], al = alpha_m[t];
        s_sigma[t] = sg; s_invsig[t] = 1.0f / sg; s_alpha[t] = al;
        s_eoa[t] = ep / al; s_eos[t] = ep / sg;
    }
    if (t < 9) s_cell[t] = cell[t];
    __syncthreads();

    float* energies = out + 1;
    float* forces   = out + 1 + n_atoms;
    float* stress   = out + 1 + 4 * n_atoms;

    float le = 0.f, s00 = 0.f, s01 = 0.f, s02 = 0.f, s11 = 0.f, s12 = 0.f, s22 = 0.f;
    const int stride = blockDim.x * gridDim.x;
    for (int p = blockIdx.x * blockDim.x + t; p < n_pairs; p += stride) {
        const int i = mapping[p], j = mapping[p + n_pairs];
        const float drx = positions[3*j]   - positions[3*i]   + shifts[3*p]*s_cell[0] + shifts[3*p+1]*s_cell[3] + shifts[3*p+2]*s_cell[6];
        const float dry = positions[3*j+1] - positions[3*i+1] + shifts[3*p]*s_cell[1] + shifts[3*p+1]*s_cell[4] + shifts[3*p+2]*s_cell[7];
        const float drz = positions[3*j+2] - positions[3*i+2] + shifts[3*p]*s_cell[2] + shifts[3*p+1]*s_cell[5] + shifts[3*p+2]*s_cell[8];
        const float r = sqrtf(drx*drx + dry*dry + drz*drz);
        const int idx = species[i] * NSP + species[j];
        if (r < s_sigma[idx]) {
            const float base = 1.0f - r * s_invsig[idx];
            const float pb = __powf(base, s_alpha[idx] - 1.0f);
            const float e = s_eoa[idx] * pb * base;
            const float sc = s_eos[idx] * pb / r;
            const float fx = sc*drx, fy = sc*dry, fz = sc*drz;
            le += e;
            s00 += drx*fx; s01 += drx*fy; s02 += drx*fz;
            s11 += dry*fy; s12 += dry*fz; s22 += drz*fz;
            atomicAdd(&energies[i], 0.5f*e); atomicAdd(&energies[j], 0.5f*e);
            atomicAdd(&forces[3*i], fx); atomicAdd(&forces[3*i+1], fy); atomicAdd(&forces[3*i+2], fz);
            atomicAdd(&forces[3*j], -fx); atomicAdd(&forces[3*j+1], -fy); atomicAdd(&forces[3*j+2], -fz);
        }
    }
    float vals[7] = {le, s00, s01, s02, s11, s12, s22};
    #pragma unroll
    for (int k = 0; k < 7; ++k) {
        float v = vals[k];
        #pragma unroll
        for (int off = 32; off > 0; off >>= 1) v += __shfl_down(v, off, 64);
        vals[k] = v;
    }
    __shared__ float s_red[4][7];
    const int wave = t >> 6, lane = t & 63;
    if (lane == 0) for (int k = 0; k < 7; ++k) s_red[wave][k] = vals[k];
    __syncthreads();
    if (t == 0) {
        const int nwaves = blockDim.x >> 6;
        float tot[7];
        for (int k = 0; k < 7; ++k) {
            float v = s_red[0][k];
            for (int w = 1; w < nwaves; ++w) v += s_red[w][k];
            tot[k] = v;
        }
        atomicAdd(&out[0], 0.5f * tot[0]);
        const float det = s_cell[0]*(s_cell[4]*s_cell[8]-s_cell[5]*s_cell[7])
                        - s_cell[1]*(s_cell[3]*s_cell[8]-s_cell[5]*s_cell[6])
                        + s_cell[2]*(s_cell[3]*s_cell[7]-s_cell[4]*s_cell[6]);
        const float nv = -1.0f / fabsf(det);
        atomicAdd(&stress[0], tot[1]*nv); atomicAdd(&stress[1], tot[2]*nv); atomicAdd(&stress[2], tot[3]*nv);
        atomicAdd(&stress[3], tot[2]*nv); atomicAdd(&stress[4], tot[4]*nv); atomicAdd(&stress[5], tot[5]*nv);
        atomicAdd(&stress[6], tot[3]*nv); atomicAdd(&stress[7], tot[5]*nv); atomicAdd(&stress[8], tot[6]*nv);
    }
}

extern "C" void kernel_launch(void* const* d_in, const int* in_sizes, int n_in,
                              void* d_out, int out_size, void* d_ws, size_t ws_size,
                              hipStream_t stream) {
    const float* positions = (const float*)d_in[0];
    const float* cell      = (const float*)d_in[1];
    const float* sigma_m   = (const float*)d_in[2];
    const float* eps_m     = (const float*)d_in[3];
    const float* alpha_m   = (const float*)d_in[4];
    const float* shifts    = (const float*)d_in[5];
    const int*   mapping   = (const int*)d_in[6];
    const int*   species   = (const int*)d_in[7];
    float* out = (float*)d_out;

    const int n_atoms = in_sizes[0] / 3;
    const int n_pairs = in_sizes[6] / 2;

    const int pk_blocks = (n_pairs + 255) / 256;   // one pair per thread
    const int rp_blocks = (n_atoms + 255) / 256;

    // ws layout (16B-aligned): accum n*16 | ps n*16 | corr 9 floats (own 128B)
    const size_t off_accum = 0;
    const size_t off_ps    = off_accum + (size_t)n_atoms * 16;
    const size_t off_corr  = off_ps    + (size_t)n_atoms * 16;
    const size_t need      = off_corr + 128;

    if (ws_size < need) {
        hipMemsetAsync(d_out, 0, (size_t)out_size * sizeof(float), stream);
        int blocks = ((n_pairs + 3) / 4 + 255) / 256;
        soft_sphere_fallback<<<blocks, 256, 0, stream>>>(
            positions, cell, sigma_m, eps_m, alpha_m, shifts, mapping, species,
            out, n_atoms, n_pairs);
        return;
    }

    char* wsb = (char*)d_ws;
    unsigned long long* accum = (unsigned long long*)(wsb + off_accum);
    v4f*                ps    = (v4f*)(wsb + off_ps);
    float*              corr  = (float*)(wsb + off_corr);

    init_kernel<<<rp_blocks, 256, 0, stream>>>(
        positions, species, ps, accum, corr, out, n_atoms);

    pair_kernel<<<pk_blocks, 256, 0, stream>>>(
        ps, cell, sigma_m, eps_m, alpha_m, shifts, mapping,
        accum, corr, n_atoms, n_pairs);

    finalize_kernel<<<FBLOCKS, 256, 0, stream>>>(
        accum, ps, corr, cell, out, n_atoms);
}

// Round 11
// 163.118 us; speedup vs baseline: 3.0238x; 1.0005x over previous
//
#include <hip/hip_runtime.h>
#include <math.h>

#define NSP 8
#define FBLOCKS 64   // finalize blocks; same-line final atomics ~640 ops (~5us), safe

typedef float v4f __attribute__((ext_vector_type(4)));

// Fixed-point packing (validated rounds 3-10, absmax 0.0039):
//  accum is 2x u64 per atom (one 16B chunk, one 64B line per pair side):
//   A = sum of ( (fx+2)*2^20 )<<32 | ( (fy+2)*2^20 )
//   B = (count)<<56 | ( he*2^17 )<<32 (24-bit field) | ( (fz+2)*2^20 )
// Hard-won rules:
//  - NO same-address global atomics from >~100 blocks (~3.5 ns/op TCC serialize: R1-R4)
//  - NO __threadfence / ticket / cooperative launch (L2-coherence storms: R7, R8)
//  - u64-packed atomics into ws beat f32 atomics into out (R3 vs R1/R8)
//  - scalar tree removed: energy = sum_a he_a, stress = sum_a r_a x F_a - K (R10)
//  - pair kernel is LATENCY-bound (R10: VALU 44->36% with no dur change);
//    this round: 2 pairs/thread, all loads front-loaded, chains overlap.
#define FSCALE 1048576.0f        /* 2^20 */
#define FINV   (1.0f/1048576.0f)
#define ESCALE 131072.0f         /* 2^17 */
#define EINV   (1.0f/131072.0f)
#define FBIAS  2.0f

// ---------------- node 1: repack pos+species -> ps; zero accum + scalar slots ----
__global__ __launch_bounds__(256) void init_kernel(
    const float* __restrict__ pos, const int* __restrict__ spec,
    v4f* __restrict__ ps, unsigned long long* __restrict__ accum,
    float* __restrict__ corr, float* __restrict__ out, int n_atoms)
{
    int t = blockIdx.x * blockDim.x + threadIdx.x;
    if (t < n_atoms) {
        v4f v;
        v.x = pos[3 * t];
        v.y = pos[3 * t + 1];
        v.z = pos[3 * t + 2];
        v.w = __int_as_float(spec[t]);
        ps[t] = v;
        accum[2 * t]     = 0ULL;
        accum[2 * t + 1] = 0ULL;
    }
    if (t == 0) out[0] = 0.f;
    if (t < 9) {
        out[1 + 4 * n_atoms + t] = 0.f;   // stress slots (finalize atomically adds)
        corr[t] = 0.f;                    // shift-correction accumulator
    }
}

// ---------------- node 2: pair kernel, TWO pairs per thread ----------------
// p0 = blockIdx*512 + t, p1 = p0 + 256 -> both stream loads coalesced.
// All stream loads + all 4 gathers issued before any compute: two latency
// chains overlap per thread.
__global__ __launch_bounds__(256, 8) void pair_kernel(
    const v4f* __restrict__ ps,
    const float* __restrict__ cell,
    const float* __restrict__ sigma_m,
    const float* __restrict__ eps_m,
    const float* __restrict__ alpha_m,
    const float* __restrict__ shifts,
    const int* __restrict__ mapping,
    unsigned long long* __restrict__ accum,  // n_atoms x 2 u64 (pre-zeroed)
    float* __restrict__ corr,                // 9 floats (pre-zeroed)
    int n_atoms, int n_pairs)
{
    __shared__ float s_sigma[64], s_invsig[64], s_alpha[64], s_eoa[64], s_eos[64];
    __shared__ float s_cell[9];
    const int t = threadIdx.x;
    if (t < 64) {
        float sg = sigma_m[t], ep = eps_m[t], al = alpha_m[t];
        s_sigma[t]  = sg;
        s_invsig[t] = 1.0f / sg;
        s_alpha[t]  = al;
        s_eoa[t]    = ep / al;
        s_eos[t]    = ep / sg;
    }
    if (t < 9) s_cell[t] = cell[t];
    __syncthreads();

    const int p0 = blockIdx.x * 512 + t;
    const int p1 = p0 + 256;

    const bool v0 = (p0 < n_pairs);
    const bool v1 = (p1 < n_pairs);
    if (!v0) return;

    // ---- front-load ALL independent loads (both pairs) ----
    const int pc1 = v1 ? p1 : p0;   // clamp second pair to a safe index

    const int i0 = mapping[p0];
    const int j0 = mapping[p0 + n_pairs];
    const int i1 = mapping[pc1];
    const int j1 = mapping[pc1 + n_pairs];

    const float sx0 = shifts[3 * p0],  sy0 = shifts[3 * p0 + 1],  sz0 = shifts[3 * p0 + 2];
    const float sx1 = shifts[3 * pc1], sy1 = shifts[3 * pc1 + 1], sz1 = shifts[3 * pc1 + 2];

    const v4f pi0 = ps[i0];
    const v4f pj0 = ps[j0];
    const v4f pi1 = ps[i1];
    const v4f pj1 = ps[j1];

    // ---- compute both pairs ----
    #pragma unroll
    for (int k = 0; k < 2; ++k) {
        if (k == 1 && !v1) break;
        const v4f   pi = k ? pi1 : pi0;
        const v4f   pj = k ? pj1 : pj0;
        const float shx = k ? sx1 : sx0;
        const float shy = k ? sy1 : sy0;
        const float shz = k ? sz1 : sz0;
        const int   i   = k ? i1 : i0;
        const int   j   = k ? j1 : j0;

        const float drx = pj.x - pi.x + shx * s_cell[0] + shy * s_cell[3] + shz * s_cell[6];
        const float dry = pj.y - pi.y + shx * s_cell[1] + shy * s_cell[4] + shz * s_cell[7];
        const float drz = pj.z - pi.z + shx * s_cell[2] + shy * s_cell[5] + shz * s_cell[8];
        const float r = sqrtf(drx * drx + dry * dry + drz * drz);

        const int idx = __float_as_int(pi.w) * NSP + __float_as_int(pj.w);
        if (r < s_sigma[idx]) {
            const float base = 1.0f - r * s_invsig[idx];
            const float pb   = __powf(base, s_alpha[idx] - 1.0f);
            const float e    = s_eoa[idx] * pb * base;
            const float sc   = s_eos[idx] * pb / r;
            const float fx = sc * drx, fy = sc * dry, fz = sc * drz;

            const float he = 0.5f * e;
            const unsigned long long he_fix = (unsigned long long)__float2uint_rn(he * ESCALE);
            {   // i side: +f
                const unsigned long long fxq = (unsigned long long)__float2uint_rn((fx + FBIAS) * FSCALE);
                const unsigned long long fyq = (unsigned long long)__float2uint_rn((fy + FBIAS) * FSCALE);
                const unsigned long long fzq = (unsigned long long)__float2uint_rn((fz + FBIAS) * FSCALE);
                atomicAdd(&accum[2 * i],     (fxq << 32) | fyq);
                atomicAdd(&accum[2 * i + 1], (1ULL << 56) | (he_fix << 32) | fzq);
            }
            {   // j side: -f
                const unsigned long long fxq = (unsigned long long)__float2uint_rn((FBIAS - fx) * FSCALE);
                const unsigned long long fyq = (unsigned long long)__float2uint_rn((FBIAS - fy) * FSCALE);
                const unsigned long long fzq = (unsigned long long)__float2uint_rn((FBIAS - fz) * FSCALE);
                atomicAdd(&accum[2 * j],     (fxq << 32) | fyq);
                atomicAdd(&accum[2 * j + 1], (1ULL << 56) | (he_fix << 32) | fzq);
            }

            // shift-correction K = sum (S.C) x f — only for nonzero shifts
            if (shx != 0.f || shy != 0.f || shz != 0.f) {
                const float scx = shx * s_cell[0] + shy * s_cell[3] + shz * s_cell[6];
                const float scy = shx * s_cell[1] + shy * s_cell[4] + shz * s_cell[7];
                const float scz = shx * s_cell[2] + shy * s_cell[5] + shz * s_cell[8];
                atomicAdd(&corr[0], scx * fx); atomicAdd(&corr[1], scx * fy); atomicAdd(&corr[2], scx * fz);
                atomicAdd(&corr[3], scy * fx); atomicAdd(&corr[4], scy * fy); atomicAdd(&corr[5], scy * fz);
                atomicAdd(&corr[6], scz * fx); atomicAdd(&corr[7], scz * fy); atomicAdd(&corr[8], scz * fz);
            }
        }
    }
}

// ---------------- node 3: decode accum -> out, and recover energy+stress ----
// energy = 0.5 * sum_a he_a;  stress = (sum_a r_a x F_a - K)/|det(cell)| * (-1)... 
// (signs as validated in R10: st = (tot - corr)/|det| with stress = -outer/V)
__global__ __launch_bounds__(256) void finalize_kernel(
    const unsigned long long* __restrict__ accum,
    const v4f* __restrict__ ps,
    const float* __restrict__ corr,
    const float* __restrict__ cell,
    float* __restrict__ out, int n_atoms)
{
    const int t  = threadIdx.x;
    const int gs = gridDim.x * 256;
    float se = 0.f, s00 = 0.f, s01 = 0.f, s02 = 0.f, s11 = 0.f, s12 = 0.f, s22 = 0.f;
    float* __restrict__ forces = out + 1 + n_atoms;

    for (int a = blockIdx.x * 256 + t; a < n_atoms; a += gs) {
        const unsigned long long A = accum[2 * a];
        const unsigned long long B = accum[2 * a + 1];
        const float cntb = (float)(unsigned)(B >> 56) * FBIAS;
        const float fx = (float)(unsigned)(A >> 32)          * FINV - cntb;
        const float fy = (float)(unsigned)(A & 0xFFFFFFFFu)  * FINV - cntb;
        const float fz = (float)(unsigned)(B & 0xFFFFFFFFu)  * FINV - cntb;
        const float he = (float)(unsigned)((B >> 32) & 0xFFFFFFu) * EINV;
        out[1 + a] = he;
        forces[3 * a]     = fx;
        forces[3 * a + 1] = fy;
        forces[3 * a + 2] = fz;

        const v4f pa = ps[a];
        se  += he;
        s00 += pa.x * fx; s01 += pa.x * fy; s02 += pa.x * fz;
        s11 += pa.y * fy; s12 += pa.y * fz; s22 += pa.z * fz;
    }

    float vals[7] = {se, s00, s01, s02, s11, s12, s22};
    #pragma unroll
    for (int k = 0; k < 7; ++k) {
        float v = vals[k];
        #pragma unroll
        for (int off = 32; off > 0; off >>= 1)
            v += __shfl_down(v, off, 64);
        vals[k] = v;
    }
    __shared__ float s_red[4][7];
    const int wave = t >> 6, lane = t & 63;
    if (lane == 0) {
        #pragma unroll
        for (int k = 0; k < 7; ++k) s_red[wave][k] = vals[k];
    }
    __syncthreads();
    if (t == 0) {
        float tot[7];
        #pragma unroll
        for (int k = 0; k < 7; ++k)
            tot[k] = s_red[0][k] + s_red[1][k] + s_red[2][k] + s_red[3][k];

        const float c0 = cell[0], c1 = cell[1], c2 = cell[2];
        const float c3 = cell[3], c4 = cell[4], c5 = cell[5];
        const float c6 = cell[6], c7 = cell[7], c8 = cell[8];
        const float det = c0 * (c4 * c8 - c5 * c7)
                        - c1 * (c3 * c8 - c5 * c6)
                        + c2 * (c3 * c7 - c4 * c6);
        const float inv = 1.0f / fabsf(det);

        atomicAdd(&out[0], 0.5f * tot[0]);
        float* st = out + 1 + 4 * n_atoms;
        atomicAdd(&st[0], tot[1] * inv);  atomicAdd(&st[1], tot[2] * inv);  atomicAdd(&st[2], tot[3] * inv);
        atomicAdd(&st[3], tot[2] * inv);  atomicAdd(&st[4], tot[4] * inv);  atomicAdd(&st[5], tot[5] * inv);
        atomicAdd(&st[6], tot[3] * inv);  atomicAdd(&st[7], tot[5] * inv);  atomicAdd(&st[8], tot[6] * inv);

        if (blockIdx.x == 0) {
            #pragma unroll
            for (int k = 0; k < 9; ++k) atomicAdd(&st[k], -corr[k] * inv);
        }
    }
}

// ---------------- last-resort fallback (ws too small) ----------------
__global__ __launch_bounds__(256) void soft_sphere_fallback(
    const float* __restrict__ positions, const float* __restrict__ cell,
    const float* __restrict__ sigma_m, const float* __restrict__ eps_m,
    const float* __restrict__ alpha_m, const float* __restrict__ shifts,
    const int* __restrict__ mapping, const int* __restrict__ species,
    float* __restrict__ out, int n_atoms, int n_pairs)
{
    __shared__ float s_sigma[64], s_invsig[64], s_alpha[64], s_eoa[64], s_eos[64];
    __shared__ float s_cell[9];
    const int t = threadIdx.x;
    if (t < 64) {
        float sg = sigma_m[t], ep = eps_m[t], al = alpha_m[t];
        s_sigma[t] = sg; s_invsig[t] = 1.0f / sg; s_alpha[t] = al;
        s_eoa[t] = ep / al; s_eos[t] = ep / sg;
    }
    if (t < 9) s_cell[t] = cell[t];
    __syncthreads();

    float* energies = out + 1;
    float* forces   = out + 1 + n_atoms;
    float* stress   = out + 1 + 4 * n_atoms;

    float le = 0.f, s00 = 0.f, s01 = 0.f, s02 = 0.f, s11 = 0.f, s12 = 0.f, s22 = 0.f;
    const int stride = blockDim.x * gridDim.x;
    for (int p = blockIdx.x * blockDim.x + t; p < n_pairs; p += stride) {
        const int i = mapping[p], j = mapping[p + n_pairs];
        const float drx = positions[3*j]   - positions[3*i]   + shifts[3*p]*s_cell[0] + shifts[3*p+1]*s_cell[3] + shifts[3*p+2]*s_cell[6];
        const float dry = positions[3*j+1] - positions[3*i+1] + shifts[3*p]*s_cell[1] + shifts[3*p+1]*s_cell[4] + shifts[3*p+2]*s_cell[7];
        const float drz = positions[3*j+2] - positions[3*i+2] + shifts[3*p]*s_cell[2] + shifts[3*p+1]*s_cell[5] + shifts[3*p+2]*s_cell[8];
        const float r = sqrtf(drx*drx + dry*dry + drz*drz);
        const int idx = species[i] * NSP + species[j];
        if (r < s_sigma[idx]) {
            const float base = 1.0f - r * s_invsig[idx];
            const float pb = __powf(base, s_alpha[idx] - 1.0f);
            const float e = s_eoa[idx] * pb * base;
            const float sc = s_eos[idx] * pb / r;
            const float fx = sc*drx, fy = sc*dry, fz = sc*drz;
            le += e;
            s00 += drx*fx; s01 += drx*fy; s02 += drx*fz;
            s11 += dry*fy; s12 += dry*fz; s22 += drz*fz;
            atomicAdd(&energies[i], 0.5f*e); atomicAdd(&energies[j], 0.5f*e);
            atomicAdd(&forces[3*i], fx); atomicAdd(&forces[3*i+1], fy); atomicAdd(&forces[3*i+2], fz);
            atomicAdd(&forces[3*j], -fx); atomicAdd(&forces[3*j+1], -fy); atomicAdd(&forces[3*j+2], -fz);
        }
    }
    float vals[7] = {le, s00, s01, s02, s11, s12, s22};
    #pragma unroll
    for (int k = 0; k < 7; ++k) {
        float v = vals[k];
        #pragma unroll
        for (int off = 32; off > 0; off >>= 1) v += __shfl_down(v, off, 64);
        vals[k] = v;
    }
    __shared__ float s_red[4][7];
    const int wave = t >> 6, lane = t & 63;
    if (lane == 0) for (int k = 0; k < 7; ++k) s_red[wave][k] = vals[k];
    __syncthreads();
    if (t == 0) {
        const int nwaves = blockDim.x >> 6;
        float tot[7];
        for (int k = 0; k < 7; ++k) {
            float v = s_red[0][k];
            for (int w = 1; w < nwaves; ++w) v += s_red[w][k];
            tot[k] = v;
        }
        atomicAdd(&out[0], 0.5f * tot[0]);
        const float det = s_cell[0]*(s_cell[4]*s_cell[8]-s_cell[5]*s_cell[7])
                        - s_cell[1]*(s_cell[3]*s_cell[8]-s_cell[5]*s_cell[6])
                        + s_cell[2]*(s_cell[3]*s_cell[7]-s_cell[4]*s_cell[6]);
        const float nv = -1.0f / fabsf(det);
        atomicAdd(&stress[0], tot[1]*nv); atomicAdd(&stress[1], tot[2]*nv); atomicAdd(&stress[2], tot[3]*nv);
        atomicAdd(&stress[3], tot[2]*nv); atomicAdd(&stress[4], tot[4]*nv); atomicAdd(&stress[5], tot[5]*nv);
        atomicAdd(&stress[6], tot[3]*nv); atomicAdd(&stress[7], tot[5]*nv); atomicAdd(&stress[8], tot[6]*nv);
    }
}

extern "C" void kernel_launch(void* const* d_in, const int* in_sizes, int n_in,
                              void* d_out, int out_size, void* d_ws, size_t ws_size,
                              hipStream_t stream) {
    const float* positions = (const float*)d_in[0];
    const float* cell      = (const float*)d_in[1];
    const float* sigma_m   = (const float*)d_in[2];
    const float* eps_m     = (const float*)d_in[3];
    const float* alpha_m   = (const float*)d_in[4];
    const float* shifts    = (const float*)d_in[5];
    const int*   mapping   = (const int*)d_in[6];
    const int*   species   = (const int*)d_in[7];
    float* out = (float*)d_out;

    const int n_atoms = in_sizes[0] / 3;
    const int n_pairs = in_sizes[6] / 2;

    const int pk_blocks = (n_pairs + 511) / 512;   // TWO pairs per thread
    const int rp_blocks = (n_atoms + 255) / 256;

    // ws layout (16B-aligned): accum n*16 | ps n*16 | corr 9 floats (own 128B)
    const size_t off_accum = 0;
    const size_t off_ps    = off_accum + (size_t)n_atoms * 16;
    const size_t off_corr  = off_ps    + (size_t)n_atoms * 16;
    const size_t need      = off_corr + 128;

    if (ws_size < need) {
        hipMemsetAsync(d_out, 0, (size_t)out_size * sizeof(float), stream);
        int blocks = ((n_pairs + 3) / 4 + 255) / 256;
        soft_sphere_fallback<<<blocks, 256, 0, stream>>>(
            positions, cell, sigma_m, eps_m, alpha_m, shifts, mapping, species,
            out, n_atoms, n_pairs);
        return;
    }

    char* wsb = (char*)d_ws;
    unsigned long long* accum = (unsigned long long*)(wsb + off_accum);
    v4f*                ps    = (v4f*)(wsb + off_ps);
    float*              corr  = (float*)(wsb + off_corr);

    init_kernel<<<rp_blocks, 256, 0, stream>>>(
        positions, species, ps, accum, corr, out, n_atoms);

    pair_kernel<<<pk_blocks, 256, 0, stream>>>(
        ps, cell, sigma_m, eps_m, alpha_m, shifts, mapping,
        accum, corr, n_atoms, n_pairs);

    finalize_kernel<<<FBLOCKS, 256, 0, stream>>>(
        accum, ps, corr, cell, out, n_atoms);
}